// Round 12
// baseline (208.288 us; speedup 1.0000x reference)
//
#include <hip/hip_runtime.h>

#define N_NODES 50000
#define N_EDGES 800000
#define CHUNKS 128
#define CHUNK_EDGES 6250      // 128 * 6250 = 800000 exactly
#define NBS 196               // ceil(50000/256) block sums, granularity 256 nodes
#define GA_BLOCKS 391         // ceil(50000/128) rows, 128 rows/block (4 waves x 32)
#define PLACE_BLOCKS 3125     // 800000 / 256

typedef __attribute__((ext_vector_type(8))) short bf16x8;
typedef __attribute__((ext_vector_type(4))) float f32x4;

static __device__ inline unsigned short bf16_rne(float x) {
    unsigned ua = __float_as_uint(x);
    return (unsigned short)((ua + 0x7fffu + ((ua >> 16) & 1u)) >> 16);
}

static __device__ inline unsigned short f16_bits(float x) {
    _Float16 hx = (_Float16)x;
    return __builtin_bit_cast(unsigned short, hx);
}

static __device__ inline float2 unpack_f16x2(unsigned u) {
    _Float16 lo = __builtin_bit_cast(_Float16, (unsigned short)(u & 0xffffu));
    _Float16 hi = __builtin_bit_cast(_Float16, (unsigned short)(u >> 16));
    return make_float2((float)lo, (float)hi);
}

// ---- launch 1: hist (blocks 0..127) || wpack (blocks 128..130) ----
__global__ __launch_bounds__(1024) void hist_wpack_kernel(const int* __restrict__ src,
                                                          const int* __restrict__ dst,
                                                          unsigned char* __restrict__ cntD,
                                                          unsigned char* __restrict__ cntS,
                                                          unsigned char* __restrict__ rp,
                                                          const float* __restrict__ W1,
                                                          const float* __restrict__ W2,
                                                          unsigned short* __restrict__ wf_hi,
                                                          unsigned short* __restrict__ wf_lo,
                                                          unsigned short* __restrict__ wf2_hi,
                                                          unsigned short* __restrict__ wf2_lo) {
    const int t = threadIdx.x;
    const int c = blockIdx.x;

    if (c >= CHUNKS) {
        int idx = (c - CHUNKS) * 1024 + t;
        if (idx < 2048) {
            int l  = idx & 63;
            int ct = (idx >> 6) & 7;
            int ks = idx >> 9;
            int col = ct * 16 + (l & 15);
            int k0  = ks * 32 + (l >> 4) * 8;
            unsigned short hi[8], lo[8];
            #pragma unroll
            for (int j = 0; j < 8; ++j) {
                float x = W1[(size_t)(k0 + j) * 128 + col];
                unsigned short h16 = bf16_rne(x);
                hi[j] = h16;
                lo[j] = bf16_rne(x - __uint_as_float((unsigned)h16 << 16));
            }
            ((uint4*)wf_hi)[idx] = *(const uint4*)hi;
            ((uint4*)wf_lo)[idx] = *(const uint4*)lo;
        } else if (idx < 3072) {
            int i2 = idx - 2048;
            int l  = i2 & 63;
            int ct = (i2 >> 6) & 3;
            int ks = i2 >> 8;
            int col = ct * 16 + (l & 15);
            int k0  = ks * 32 + (l >> 4) * 8;
            unsigned short hi[8], lo[8];
            #pragma unroll
            for (int j = 0; j < 8; ++j) {
                float x = W2[(size_t)(k0 + j) * 64 + col];
                unsigned short h16 = bf16_rne(x);
                hi[j] = h16;
                lo[j] = bf16_rne(x - __uint_as_float((unsigned)h16 << 16));
            }
            ((uint4*)wf2_hi)[i2] = *(const uint4*)hi;
            ((uint4*)wf2_lo)[i2] = *(const uint4*)lo;
        }
        return;
    }

    __shared__ unsigned hD[12500];
    __shared__ unsigned hS[12500];
    for (int i = t; i < 12500; i += 1024) { hD[i] = 0u; hS[i] = 0u; }
    __syncthreads();

    const int base = c * CHUNK_EDGES;
    for (int i = t; i < CHUNK_EDGES; i += 1024) {
        int e = base + i;
        int d = dst[e];
        int s = src[e];
        unsigned shd = (unsigned)(d & 3) * 8u;
        unsigned old = atomicAdd(&hD[d >> 2], 1u << shd);
        rp[e] = (unsigned char)((old >> shd) & 0xffu);
        atomicAdd(&hS[s >> 2], 1u << ((unsigned)(s & 3) * 8u));
    }
    __syncthreads();

    unsigned* gD = (unsigned*)cntD + (size_t)c * 12500;
    unsigned* gS = (unsigned*)cntS + (size_t)c * 12500;
    for (int i = t; i < 12500; i += 1024) { gD[i] = hD[i]; gS[i] = hS[i]; }
}

// ---- launch 2: per-node chunk prefix + norms + block scan + (last block) bsum scan ----
__global__ __launch_bounds__(256) void deg_scan_kernel(unsigned char* __restrict__ cntD,
                                                       const unsigned char* __restrict__ cntS,
                                                       int* __restrict__ row_ptr,
                                                       int* __restrict__ bsum,
                                                       float* __restrict__ norm_out,
                                                       float* __restrict__ norm_in,
                                                       int* __restrict__ done) {
    const int t = threadIdx.x, lane = t & 63, w = t >> 6;
    const int n = blockIdx.x * 256 + t;
    unsigned sumD = 0u, sumS = 0u;
    if (n < N_NODES) {
        #pragma unroll 4
        for (int c = 0; c < CHUNKS; ++c) {
            size_t idx = (size_t)c * 50000 + n;
            unsigned v = cntD[idx];
            cntD[idx] = (unsigned char)sumD;   // exclusive prefix (total deg < 256)
            sumD += v;
            sumS += cntS[idx];
        }
        norm_in[n]  = rsqrtf((float)(sumD ? sumD : 1u));
        norm_out[n] = rsqrtf((float)(sumS ? sumS : 1u));
    }
    __shared__ int wsum[4];
    __shared__ int is_last;
    int v = (n < N_NODES) ? (int)sumD : 0;
    int incl = v;
    #pragma unroll
    for (int d = 1; d < 64; d <<= 1) {
        int u = __shfl_up(incl, d, 64);
        if (lane >= d) incl += u;
    }
    if (lane == 63) wsum[w] = incl;
    __syncthreads();
    int woff = 0, total = 0;
    #pragma unroll
    for (int j = 0; j < 4; ++j) {
        int s = wsum[j];
        if (j < w) woff += s;
        total += s;
    }
    if (n < N_NODES) row_ptr[n] = woff + incl - v;
    if (t == 0) bsum[blockIdx.x] = total;

    // last block to finish performs the 196-element bsum exclusive scan
    if (t == 0) {
        __threadfence();
        int ticket = atomicAdd(done, 1);
        is_last = (ticket == NBS - 1) ? 1 : 0;
    }
    __syncthreads();
    if (is_last && t < 64) {
        __threadfence();
        int carry = 0;
        for (int base = 0; base < NBS; base += 64) {
            int i = base + t;
            int bv = (i < NBS) ? bsum[i] : 0;
            int bincl = bv;
            #pragma unroll
            for (int d = 1; d < 64; d <<= 1) {
                int u = __shfl_up(bincl, d, 64);
                if (t >= d) bincl += u;
            }
            int excl = carry + bincl - bv;
            if (i < NBS) bsum[i] = excl;
            if (i == NBS - 1) row_ptr[N_NODES] = N_EDGES - excl;
            carry += __shfl(bincl, 63, 64);
        }
    }
}

// ---- launch 3: gemmA (blocks 0..390) || place (blocks 391..3515) ----
__global__ __launch_bounds__(256) void gemmA_place_kernel(const float* __restrict__ h,
                                                          const unsigned short* __restrict__ wf_hi,
                                                          const unsigned short* __restrict__ wf_lo,
                                                          const float* __restrict__ norm_out,
                                                          unsigned short* __restrict__ t1,
                                                          const int* __restrict__ src,
                                                          const int* __restrict__ dst,
                                                          const int* __restrict__ row_ptr,
                                                          const int* __restrict__ bsum,
                                                          const unsigned char* __restrict__ cntD,
                                                          const unsigned char* __restrict__ rp,
                                                          int* __restrict__ eidx) {
    if (blockIdx.x >= GA_BLOCKS) {
        int e = (blockIdx.x - GA_BLOCKS) * 256 + threadIdx.x;
        if (e < N_EDGES) {
            int d = dst[e];
            int c = e / CHUNK_EDGES;
            int pos = row_ptr[d] + bsum[d >> 8] + (int)cntD[(size_t)c * 50000 + d]
                    + (int)rp[e];
            eidx[pos] = src[e];
        }
        return;
    }

    const int t  = threadIdx.x;
    const int wv = t >> 6;
    const int l  = t & 63;
    const int lrow = l & 15;
    const int g    = l >> 4;
    const int n0 = blockIdx.x * 128 + wv * 32;

    int r0 = n0 + lrow;      if (r0 > N_NODES - 1) r0 = N_NODES - 1;
    int r1 = n0 + 16 + lrow; if (r1 > N_NODES - 1) r1 = N_NODES - 1;
    const float* h0 = h + (size_t)r0 * 128 + g * 8;
    const float* h1 = h + (size_t)r1 * 128 + g * 8;

    f32x4 acc[2][8];
    #pragma unroll
    for (int rt = 0; rt < 2; ++rt)
        #pragma unroll
        for (int ct = 0; ct < 8; ++ct)
            acc[rt][ct] = (f32x4){0.f, 0.f, 0.f, 0.f};

    const bf16x8* bh_base = (const bf16x8*)wf_hi;
    const bf16x8* bl_base = (const bf16x8*)wf_lo;

    for (int ks = 0; ks < 4; ++ks) {
        float a0[8], a1[8];
        *(float4*)(a0)     = *(const float4*)(h0 + ks * 32);
        *(float4*)(a0 + 4) = *(const float4*)(h0 + ks * 32 + 4);
        *(float4*)(a1)     = *(const float4*)(h1 + ks * 32);
        *(float4*)(a1 + 4) = *(const float4*)(h1 + ks * 32 + 4);

        bf16x8 a0h, a0l, a1h, a1l;
        #pragma unroll
        for (int j = 0; j < 8; ++j) {
            unsigned short hh = bf16_rne(a0[j]);
            a0h[j] = (short)hh;
            a0l[j] = (short)bf16_rne(a0[j] - __uint_as_float((unsigned)hh << 16));
            unsigned short h2 = bf16_rne(a1[j]);
            a1h[j] = (short)h2;
            a1l[j] = (short)bf16_rne(a1[j] - __uint_as_float((unsigned)h2 << 16));
        }

        #pragma unroll
        for (int ct = 0; ct < 8; ++ct) {
            const int fi = (ks * 8 + ct) * 64 + l;
            bf16x8 bh = bh_base[fi];
            bf16x8 bl = bl_base[fi];
            acc[0][ct] = __builtin_amdgcn_mfma_f32_16x16x32_bf16(a0l, bh, acc[0][ct], 0, 0, 0);
            acc[0][ct] = __builtin_amdgcn_mfma_f32_16x16x32_bf16(a0h, bl, acc[0][ct], 0, 0, 0);
            acc[0][ct] = __builtin_amdgcn_mfma_f32_16x16x32_bf16(a0h, bh, acc[0][ct], 0, 0, 0);
            acc[1][ct] = __builtin_amdgcn_mfma_f32_16x16x32_bf16(a1l, bh, acc[1][ct], 0, 0, 0);
            acc[1][ct] = __builtin_amdgcn_mfma_f32_16x16x32_bf16(a1h, bl, acc[1][ct], 0, 0, 0);
            acc[1][ct] = __builtin_amdgcn_mfma_f32_16x16x32_bf16(a1h, bh, acc[1][ct], 0, 0, 0);
        }
    }

    #pragma unroll
    for (int rt = 0; rt < 2; ++rt) {
        float no_[4];
        #pragma unroll
        for (int r = 0; r < 4; ++r) {
            int row = n0 + rt * 16 + g * 4 + r;
            no_[r] = (row < N_NODES) ? norm_out[row] : 0.f;
        }
        #pragma unroll
        for (int ct = 0; ct < 8; ++ct) {
            #pragma unroll
            for (int r = 0; r < 4; ++r) {
                int row = n0 + rt * 16 + g * 4 + r;
                if (row < N_NODES)
                    t1[(size_t)row * 128 + ct * 16 + lrow] = bf16_rne(acc[rt][ct][r] * no_[r]);
            }
        }
    }
}

// ---------------- GEMM-B via MFMA (bf16x3): t2 = fp16(h1p @ W2) ----------------
__global__ __launch_bounds__(256) void gemmB_kernel(const float* __restrict__ h1p,
                                                    const unsigned short* __restrict__ wf2_hi,
                                                    const unsigned short* __restrict__ wf2_lo,
                                                    unsigned short* __restrict__ t2h) {
    const int t  = threadIdx.x;
    const int wv = t >> 6;
    const int l  = t & 63;
    const int lrow = l & 15;
    const int g    = l >> 4;
    const int n0 = blockIdx.x * 128 + wv * 32;

    int r0 = n0 + lrow;      if (r0 > N_NODES - 1) r0 = N_NODES - 1;
    int r1 = n0 + 16 + lrow; if (r1 > N_NODES - 1) r1 = N_NODES - 1;
    const float* h0 = h1p + (size_t)r0 * 128 + g * 8;
    const float* h1 = h1p + (size_t)r1 * 128 + g * 8;

    f32x4 acc[2][4];
    #pragma unroll
    for (int rt = 0; rt < 2; ++rt)
        #pragma unroll
        for (int ct = 0; ct < 4; ++ct)
            acc[rt][ct] = (f32x4){0.f, 0.f, 0.f, 0.f};

    const bf16x8* bh_base = (const bf16x8*)wf2_hi;
    const bf16x8* bl_base = (const bf16x8*)wf2_lo;

    for (int ks = 0; ks < 4; ++ks) {
        float a0[8], a1[8];
        *(float4*)(a0)     = *(const float4*)(h0 + ks * 32);
        *(float4*)(a0 + 4) = *(const float4*)(h0 + ks * 32 + 4);
        *(float4*)(a1)     = *(const float4*)(h1 + ks * 32);
        *(float4*)(a1 + 4) = *(const float4*)(h1 + ks * 32 + 4);

        bf16x8 a0h, a0l, a1h, a1l;
        #pragma unroll
        for (int j = 0; j < 8; ++j) {
            unsigned short hh = bf16_rne(a0[j]);
            a0h[j] = (short)hh;
            a0l[j] = (short)bf16_rne(a0[j] - __uint_as_float((unsigned)hh << 16));
            unsigned short h2 = bf16_rne(a1[j]);
            a1h[j] = (short)h2;
            a1l[j] = (short)bf16_rne(a1[j] - __uint_as_float((unsigned)h2 << 16));
        }

        #pragma unroll
        for (int ct = 0; ct < 4; ++ct) {
            const int fi = (ks * 4 + ct) * 64 + l;
            bf16x8 bh = bh_base[fi];
            bf16x8 bl = bl_base[fi];
            acc[0][ct] = __builtin_amdgcn_mfma_f32_16x16x32_bf16(a0l, bh, acc[0][ct], 0, 0, 0);
            acc[0][ct] = __builtin_amdgcn_mfma_f32_16x16x32_bf16(a0h, bl, acc[0][ct], 0, 0, 0);
            acc[0][ct] = __builtin_amdgcn_mfma_f32_16x16x32_bf16(a0h, bh, acc[0][ct], 0, 0, 0);
            acc[1][ct] = __builtin_amdgcn_mfma_f32_16x16x32_bf16(a1l, bh, acc[1][ct], 0, 0, 0);
            acc[1][ct] = __builtin_amdgcn_mfma_f32_16x16x32_bf16(a1h, bl, acc[1][ct], 0, 0, 0);
            acc[1][ct] = __builtin_amdgcn_mfma_f32_16x16x32_bf16(a1h, bh, acc[1][ct], 0, 0, 0);
        }
    }

    #pragma unroll
    for (int rt = 0; rt < 2; ++rt) {
        #pragma unroll
        for (int ct = 0; ct < 4; ++ct) {
            #pragma unroll
            for (int r = 0; r < 4; ++r) {
                int row = n0 + rt * 16 + g * 4 + r;
                if (row < N_NODES)
                    t2h[(size_t)row * 64 + ct * 16 + lrow] = f16_bits(acc[rt][ct][r]);
            }
        }
    }
}

// ---------------- pull aggregation, 128 bf16 feats: one wave per node ----------------
// 16 gathers in flight per iteration (avg degree ~16 -> one iteration typical).
__global__ __launch_bounds__(256) void pull128_kernel(const unsigned short* __restrict__ xb,
                                                      const int* __restrict__ row_ptr,
                                                      const int* __restrict__ bsum,
                                                      const int* __restrict__ eidx,
                                                      const float* __restrict__ b1,
                                                      const float* __restrict__ norm_in,
                                                      const float* __restrict__ norm_out,
                                                      float* __restrict__ out) {
    int node = blockIdx.x * 4 + (threadIdx.x >> 6);
    node = __builtin_amdgcn_readfirstlane(node);
    const int lane = threadIdx.x & 63;
    const int beg = __builtin_amdgcn_readfirstlane(row_ptr[node] + bsum[node >> 8]);
    const int end = __builtin_amdgcn_readfirstlane(row_ptr[node + 1] + bsum[(node + 1) >> 8]);

    float2 acc[4];
    #pragma unroll
    for (int j = 0; j < 4; ++j) acc[j] = make_float2(0.f, 0.f);

    for (int base = beg; base < end; base += 64) {
        const int cnt = min(64, end - base);
        int my_e = (lane < cnt) ? eidx[base + lane] : 0;
        int k = 0;
        for (; k + 15 < cnt; k += 16) {       // 16 gathers in flight
            unsigned u[16];
            #pragma unroll
            for (int j = 0; j < 16; ++j) {
                int s = __builtin_amdgcn_readlane(my_e, k + j);
                u[j] = ((const unsigned*)(xb + (size_t)s * 128))[lane];
            }
            #pragma unroll
            for (int j = 0; j < 16; ++j) {
                acc[j & 3].x += __uint_as_float(u[j] << 16);
                acc[j & 3].y += __uint_as_float(u[j] & 0xffff0000u);
            }
        }
        for (; k + 7 < cnt; k += 8) {
            unsigned u[8];
            #pragma unroll
            for (int j = 0; j < 8; ++j) {
                int s = __builtin_amdgcn_readlane(my_e, k + j);
                u[j] = ((const unsigned*)(xb + (size_t)s * 128))[lane];
            }
            #pragma unroll
            for (int j = 0; j < 8; ++j) {
                acc[j & 3].x += __uint_as_float(u[j] << 16);
                acc[j & 3].y += __uint_as_float(u[j] & 0xffff0000u);
            }
        }
        for (; k + 3 < cnt; k += 4) {
            unsigned u[4];
            #pragma unroll
            for (int j = 0; j < 4; ++j) {
                int s = __builtin_amdgcn_readlane(my_e, k + j);
                u[j] = ((const unsigned*)(xb + (size_t)s * 128))[lane];
            }
            #pragma unroll
            for (int j = 0; j < 4; ++j) {
                acc[j & 3].x += __uint_as_float(u[j] << 16);
                acc[j & 3].y += __uint_as_float(u[j] & 0xffff0000u);
            }
        }
        for (; k < cnt; ++k) {
            int s = __builtin_amdgcn_readlane(my_e, k);
            unsigned u0 = ((const unsigned*)(xb + (size_t)s * 128))[lane];
            acc[0].x += __uint_as_float(u0 << 16);
            acc[0].y += __uint_as_float(u0 & 0xffff0000u);
        }
    }

    float ni = norm_in[node];
    float no = norm_out[node];
    float2 bb = ((const float2*)b1)[lane];
    float sx = (acc[0].x + acc[1].x) + (acc[2].x + acc[3].x);
    float sy = (acc[0].y + acc[1].y) + (acc[2].y + acc[3].y);
    float2 r;
    r.x = fmaxf(fmaf(sx, ni, bb.x), 0.f) * no;
    r.y = fmaxf(fmaf(sy, ni, bb.y), 0.f) * no;
    ((float2*)(out + (size_t)node * 128))[lane] = r;
}

// ---------------- pull aggregation, 64 fp16 feats, 2 edges per wave-round ----------------
// 16-edge main loop -> 8 loads in flight per lane.
__global__ __launch_bounds__(256) void pull64_kernel(const unsigned* __restrict__ x,
                                                     const int* __restrict__ row_ptr,
                                                     const int* __restrict__ bsum,
                                                     const int* __restrict__ eidx,
                                                     const float* __restrict__ b2,
                                                     const float* __restrict__ norm_in,
                                                     float* __restrict__ out) {
    int node = blockIdx.x * 4 + (threadIdx.x >> 6);
    node = __builtin_amdgcn_readfirstlane(node);
    const int lane = threadIdx.x & 63;
    const int half = lane >> 5;
    const int fl = lane & 31;
    const int beg = __builtin_amdgcn_readfirstlane(row_ptr[node] + bsum[node >> 8]);
    const int end = __builtin_amdgcn_readfirstlane(row_ptr[node + 1] + bsum[(node + 1) >> 8]);

    float2 a[4];
    #pragma unroll
    for (int j = 0; j < 4; ++j) a[j] = make_float2(0.f, 0.f);

    for (int base = beg; base < end; base += 64) {
        const int cnt = min(64, end - base);
        int my_e = (lane < cnt) ? eidx[base + lane] : 0;
        int k = 0;
        for (; k + 15 < cnt; k += 16) {       // 8 loads in flight
            unsigned u[8];
            #pragma unroll
            for (int j = 0; j < 8; ++j) {
                int sa = __builtin_amdgcn_readlane(my_e, k + 2 * j);
                int sb = __builtin_amdgcn_readlane(my_e, k + 2 * j + 1);
                int e0 = half ? sb : sa;
                u[j] = x[(size_t)e0 * 32 + fl];
            }
            #pragma unroll
            for (int j = 0; j < 8; ++j) {
                float2 v = unpack_f16x2(u[j]);
                a[j & 3].x += v.x; a[j & 3].y += v.y;
            }
        }
        for (; k + 7 < cnt; k += 8) {
            unsigned u[4];
            #pragma unroll
            for (int j = 0; j < 4; ++j) {
                int sa = __builtin_amdgcn_readlane(my_e, k + 2 * j);
                int sb = __builtin_amdgcn_readlane(my_e, k + 2 * j + 1);
                int e0 = half ? sb : sa;
                u[j] = x[(size_t)e0 * 32 + fl];
            }
            #pragma unroll
            for (int j = 0; j < 4; ++j) {
                float2 v = unpack_f16x2(u[j]);
                a[j & 3].x += v.x; a[j & 3].y += v.y;
            }
        }
        for (; k + 1 < cnt; k += 2) {
            int sa = __builtin_amdgcn_readlane(my_e, k);
            int sb = __builtin_amdgcn_readlane(my_e, k + 1);
            int e0 = half ? sb : sa;
            unsigned u = x[(size_t)e0 * 32 + fl];
            float2 v = unpack_f16x2(u);
            a[0].x += v.x; a[0].y += v.y;
        }
        if (k < cnt) {
            int sa = __builtin_amdgcn_readlane(my_e, k);
            if (half == 0) {
                unsigned u = x[(size_t)sa * 32 + fl];
                float2 v = unpack_f16x2(u);
                a[0].x += v.x; a[0].y += v.y;
            }
        }
    }

    float ax = (a[0].x + a[1].x) + (a[2].x + a[3].x);
    float ay = (a[0].y + a[1].y) + (a[2].y + a[3].y);
    ax += __shfl_xor(ax, 32, 64);
    ay += __shfl_xor(ay, 32, 64);
    if (half == 0) {
        float ni = norm_in[node];
        float2 bb = ((const float2*)b2)[fl];
        float2 r;
        r.x = fmaxf(fmaf(ax, ni, bb.x), 0.f);
        r.y = fmaxf(fmaf(ay, ni, bb.y), 0.f);
        ((float2*)(out + (size_t)node * 64))[fl] = r;
    }
}

extern "C" void kernel_launch(void* const* d_in, const int* in_sizes, int n_in,
                              void* d_out, int out_size, void* d_ws, size_t ws_size,
                              hipStream_t stream) {
    const float* h  = (const float*)d_in[0];
    const float* W1 = (const float*)d_in[1];
    const float* b1 = (const float*)d_in[2];
    const float* W2 = (const float*)d_in[3];
    const float* b2 = (const float*)d_in[4];
    const int* src  = (const int*)d_in[5];
    const int* dst  = (const int*)d_in[6];
    float* out = (float*)d_out;

    char* ws = (char*)d_ws;
    size_t off = 0;
    auto alloc = [&](size_t bytes) {
        void* p = ws + off;
        off = (off + bytes + 255) & ~(size_t)255;
        return p;
    };
    float* norm_out   = (float*)alloc(N_NODES * sizeof(float));
    float* norm_in    = (float*)alloc(N_NODES * sizeof(float));
    int* row_ptr      = (int*)alloc((N_NODES + 1) * sizeof(int));
    int* bsum         = (int*)alloc(NBS * sizeof(int));
    int* done         = (int*)alloc(sizeof(int));
    unsigned short* wf_hi  = (unsigned short*)alloc(2048 * 16);
    unsigned short* wf_lo  = (unsigned short*)alloc(2048 * 16);
    unsigned short* wf2_hi = (unsigned short*)alloc(1024 * 16);
    unsigned short* wf2_lo = (unsigned short*)alloc(1024 * 16);
    int* eidx         = (int*)alloc((size_t)N_EDGES * sizeof(int));
    unsigned short* t1 = (unsigned short*)alloc((size_t)N_NODES * 128 * sizeof(short));
    float* h1p        = (float*)alloc((size_t)N_NODES * 128 * sizeof(float));

    unsigned char* cntD = (unsigned char*)h1p;
    unsigned char* cntS = cntD + (size_t)CHUNKS * 50000;
    unsigned char* rp   = cntS + (size_t)CHUNKS * 50000;
    unsigned short* t2h = t1;

    hipMemsetAsync(done, 0, sizeof(int), stream);

    // launch 1: histogram || W-pack
    hist_wpack_kernel<<<CHUNKS + 3, 1024, 0, stream>>>(src, dst, cntD, cntS, rp,
                                                       W1, W2, wf_hi, wf_lo, wf2_hi, wf2_lo);

    // launch 2: chunk prefix + norms + block scan + fused bsum scan (last block)
    deg_scan_kernel<<<NBS, 256, 0, stream>>>(cntD, cntS, row_ptr, bsum,
                                             norm_out, norm_in, done);

    // launch 3: gemmA (MFMA bf16x3, norm folded) || CSR placement
    gemmA_place_kernel<<<GA_BLOCKS + PLACE_BLOCKS, 256, 0, stream>>>(
        h, wf_hi, wf_lo, norm_out, t1, src, dst, row_ptr, bsum, cntD, rp, eidx);

    // launch 4: layer 1 pull
    pull128_kernel<<<N_NODES / 4, 256, 0, stream>>>(t1, row_ptr, bsum, eidx, b1,
                                                    norm_in, norm_out, h1p);

    // launch 5: gemmB
    gemmB_kernel<<<GA_BLOCKS, 256, 0, stream>>>(h1p, wf2_hi, wf2_lo, t2h);

    // launch 6: layer 2 pull
    pull64_kernel<<<N_NODES / 4, 256, 0, stream>>>((const unsigned*)t2h, row_ptr, bsum, eidx,
                                                   b2, norm_in, out);
}

// Round 13
// 200.283 us; speedup vs baseline: 1.0400x; 1.0400x over previous
//
#include <hip/hip_runtime.h>

#define N_NODES 50000
#define N_EDGES 800000
#define CHUNKS 128
#define CHUNK_EDGES 6250      // 128 * 6250 = 800000 exactly
#define NBS 196               // ceil(50000/256) block sums, granularity 256 nodes
#define GA_BLOCKS 391         // ceil(50000/128) rows, 128 rows/block (4 waves x 32)
#define PLACE_BLOCKS 3125     // 800000 / 256

typedef __attribute__((ext_vector_type(8))) short bf16x8;
typedef __attribute__((ext_vector_type(4))) float f32x4;

static __device__ inline unsigned short bf16_rne(float x) {
    unsigned ua = __float_as_uint(x);
    return (unsigned short)((ua + 0x7fffu + ((ua >> 16) & 1u)) >> 16);
}

static __device__ inline unsigned short f16_bits(float x) {
    _Float16 hx = (_Float16)x;
    return __builtin_bit_cast(unsigned short, hx);
}

static __device__ inline float f16_val(unsigned short u) {
    return (float)__builtin_bit_cast(_Float16, u);
}

static __device__ inline float2 unpack_f16x2(unsigned u) {
    _Float16 lo = __builtin_bit_cast(_Float16, (unsigned short)(u & 0xffffu));
    _Float16 hi = __builtin_bit_cast(_Float16, (unsigned short)(u >> 16));
    return make_float2((float)lo, (float)hi);
}

// ---- launch 1: hist half-chunks (blocks 0..255) || wpack (blocks 256..258) ----
// Each chunk is handled by TWO blocks, each owning a 25k-node half (50 KB LDS
// -> 2 blocks/CU, all 256 CUs busy). Edges read twice; counts/ranks owned by
// exactly one half-block, so semantics identical to the full-chunk version.
__global__ __launch_bounds__(1024) void hist_wpack_kernel(const int* __restrict__ src,
                                                          const int* __restrict__ dst,
                                                          unsigned char* __restrict__ cntD,
                                                          unsigned char* __restrict__ cntS,
                                                          unsigned char* __restrict__ rp,
                                                          const float* __restrict__ W1,
                                                          const float* __restrict__ W2,
                                                          unsigned short* __restrict__ wf_hi,
                                                          unsigned short* __restrict__ wf_lo,
                                                          unsigned short* __restrict__ wf2_hi,
                                                          unsigned short* __restrict__ wf2_lo) {
    const int t = threadIdx.x;
    const int b = blockIdx.x;

    if (b >= 2 * CHUNKS) {
        int idx = (b - 2 * CHUNKS) * 1024 + t;
        if (idx < 2048) {
            int l  = idx & 63;
            int ct = (idx >> 6) & 7;
            int ks = idx >> 9;
            int col = ct * 16 + (l & 15);
            int k0  = ks * 32 + (l >> 4) * 8;
            unsigned short hi[8], lo[8];
            #pragma unroll
            for (int j = 0; j < 8; ++j) {
                float x = W1[(size_t)(k0 + j) * 128 + col];
                unsigned short h16 = bf16_rne(x);
                hi[j] = h16;
                lo[j] = bf16_rne(x - __uint_as_float((unsigned)h16 << 16));
            }
            ((uint4*)wf_hi)[idx] = *(const uint4*)hi;
            ((uint4*)wf_lo)[idx] = *(const uint4*)lo;
        } else if (idx < 3072) {
            int i2 = idx - 2048;
            int l  = i2 & 63;
            int ct = (i2 >> 6) & 3;
            int ks = i2 >> 8;
            int col = ct * 16 + (l & 15);
            int k0  = ks * 32 + (l >> 4) * 8;
            unsigned short hi[8], lo[8];
            #pragma unroll
            for (int j = 0; j < 8; ++j) {
                float x = W2[(size_t)(k0 + j) * 64 + col];
                unsigned short h16 = bf16_rne(x);
                hi[j] = h16;
                lo[j] = bf16_rne(x - __uint_as_float((unsigned)h16 << 16));
            }
            ((uint4*)wf2_hi)[i2] = *(const uint4*)hi;
            ((uint4*)wf2_lo)[i2] = *(const uint4*)lo;
        }
        return;
    }

    const int c    = b >> 1;
    const int half = b & 1;
    const int nbase = half * 25000;     // first node of this half

    __shared__ unsigned hD[6250];       // 25000 8-bit counters (dst, this half)
    __shared__ unsigned hS[6250];       // 25000 8-bit counters (src, this half)
    for (int i = t; i < 6250; i += 1024) { hD[i] = 0u; hS[i] = 0u; }
    __syncthreads();

    const int base = c * CHUNK_EDGES;
    for (int i = t; i < CHUNK_EDGES; i += 1024) {
        int e = base + i;
        int d = dst[e];
        int s = src[e];
        unsigned dn = (unsigned)(d - nbase);
        if (dn < 25000u) {
            unsigned shd = (dn & 3u) * 8u;
            unsigned old = atomicAdd(&hD[dn >> 2], 1u << shd);
            rp[e] = (unsigned char)((old >> shd) & 0xffu);
        }
        unsigned sn = (unsigned)(s - nbase);
        if (sn < 25000u)
            atomicAdd(&hS[sn >> 2], 1u << ((sn & 3u) * 8u));
    }
    __syncthreads();

    unsigned* gD = (unsigned*)cntD + (size_t)c * 12500 + half * 6250;
    unsigned* gS = (unsigned*)cntS + (size_t)c * 12500 + half * 6250;
    for (int i = t; i < 6250; i += 1024) { gD[i] = hD[i]; gS[i] = hS[i]; }
}

// ---- launch 2: per-node chunk prefix (in-place) + norms + block-level scan ----
__global__ __launch_bounds__(256) void deg_scan_kernel(unsigned char* __restrict__ cntD,
                                                       const unsigned char* __restrict__ cntS,
                                                       int* __restrict__ row_ptr,
                                                       int* __restrict__ bsum,
                                                       float* __restrict__ norm_out,
                                                       float* __restrict__ norm_in) {
    const int t = threadIdx.x, lane = t & 63, w = t >> 6;
    const int n = blockIdx.x * 256 + t;
    unsigned sumD = 0u, sumS = 0u;
    if (n < N_NODES) {
        #pragma unroll 4
        for (int c = 0; c < CHUNKS; ++c) {
            size_t idx = (size_t)c * 50000 + n;
            unsigned v = cntD[idx];
            cntD[idx] = (unsigned char)sumD;   // exclusive prefix (total deg < 256)
            sumD += v;
            sumS += cntS[idx];
        }
        norm_in[n]  = rsqrtf((float)(sumD ? sumD : 1u));
        norm_out[n] = rsqrtf((float)(sumS ? sumS : 1u));
    }
    __shared__ int wsum[4];
    int v = (n < N_NODES) ? (int)sumD : 0;
    int incl = v;
    #pragma unroll
    for (int d = 1; d < 64; d <<= 1) {
        int u = __shfl_up(incl, d, 64);
        if (lane >= d) incl += u;
    }
    if (lane == 63) wsum[w] = incl;
    __syncthreads();
    int woff = 0, total = 0;
    #pragma unroll
    for (int j = 0; j < 4; ++j) {
        int s = wsum[j];
        if (j < w) woff += s;
        total += s;
    }
    if (n < N_NODES) row_ptr[n] = woff + incl - v;
    if (t == 0) bsum[blockIdx.x] = total;
}

// ---- launch 3: scan of 196 block sums (single wave, chunks with carry) ----
__global__ __launch_bounds__(64) void scan2_kernel(int* __restrict__ bsum,
                                                   int* __restrict__ row_ptr) {
    const int lane = threadIdx.x;
    int carry = 0;
    for (int base = 0; base < NBS; base += 64) {
        int t = base + lane;
        int v = (t < NBS) ? bsum[t] : 0;
        int incl = v;
        #pragma unroll
        for (int d = 1; d < 64; d <<= 1) {
            int u = __shfl_up(incl, d, 64);
            if (lane >= d) incl += u;
        }
        int excl = carry + incl - v;
        if (t < NBS) bsum[t] = excl;
        if (t == NBS - 1) row_ptr[N_NODES] = N_EDGES - excl;
        carry += __shfl(incl, 63, 64);
    }
}

// ---- launch 4: gemmA (blocks 0..390) || place (blocks 391..3515) ----
__global__ __launch_bounds__(256) void gemmA_place_kernel(const float* __restrict__ h,
                                                          const unsigned short* __restrict__ wf_hi,
                                                          const unsigned short* __restrict__ wf_lo,
                                                          const float* __restrict__ norm_out,
                                                          unsigned short* __restrict__ t1,
                                                          const int* __restrict__ src,
                                                          const int* __restrict__ dst,
                                                          const int* __restrict__ row_ptr,
                                                          const int* __restrict__ bsum,
                                                          const unsigned char* __restrict__ cntD,
                                                          const unsigned char* __restrict__ rp,
                                                          int* __restrict__ eidx) {
    if (blockIdx.x >= GA_BLOCKS) {
        int e = (blockIdx.x - GA_BLOCKS) * 256 + threadIdx.x;
        if (e < N_EDGES) {
            int d = dst[e];
            int c = e / CHUNK_EDGES;
            int pos = row_ptr[d] + bsum[d >> 8] + (int)cntD[(size_t)c * 50000 + d]
                    + (int)rp[e];
            eidx[pos] = src[e];
        }
        return;
    }

    const int t  = threadIdx.x;
    const int wv = t >> 6;
    const int l  = t & 63;
    const int lrow = l & 15;
    const int g    = l >> 4;
    const int n0 = blockIdx.x * 128 + wv * 32;

    int r0 = n0 + lrow;      if (r0 > N_NODES - 1) r0 = N_NODES - 1;
    int r1 = n0 + 16 + lrow; if (r1 > N_NODES - 1) r1 = N_NODES - 1;
    const float* h0 = h + (size_t)r0 * 128 + g * 8;
    const float* h1 = h + (size_t)r1 * 128 + g * 8;

    f32x4 acc[2][8];
    #pragma unroll
    for (int rt = 0; rt < 2; ++rt)
        #pragma unroll
        for (int ct = 0; ct < 8; ++ct)
            acc[rt][ct] = (f32x4){0.f, 0.f, 0.f, 0.f};

    const bf16x8* bh_base = (const bf16x8*)wf_hi;
    const bf16x8* bl_base = (const bf16x8*)wf_lo;

    for (int ks = 0; ks < 4; ++ks) {
        float a0[8], a1[8];
        *(float4*)(a0)     = *(const float4*)(h0 + ks * 32);
        *(float4*)(a0 + 4) = *(const float4*)(h0 + ks * 32 + 4);
        *(float4*)(a1)     = *(const float4*)(h1 + ks * 32);
        *(float4*)(a1 + 4) = *(const float4*)(h1 + ks * 32 + 4);

        bf16x8 a0h, a0l, a1h, a1l;
        #pragma unroll
        for (int j = 0; j < 8; ++j) {
            unsigned short hh = bf16_rne(a0[j]);
            a0h[j] = (short)hh;
            a0l[j] = (short)bf16_rne(a0[j] - __uint_as_float((unsigned)hh << 16));
            unsigned short h2 = bf16_rne(a1[j]);
            a1h[j] = (short)h2;
            a1l[j] = (short)bf16_rne(a1[j] - __uint_as_float((unsigned)h2 << 16));
        }

        #pragma unroll
        for (int ct = 0; ct < 8; ++ct) {
            const int fi = (ks * 8 + ct) * 64 + l;
            bf16x8 bh = bh_base[fi];
            bf16x8 bl = bl_base[fi];
            acc[0][ct] = __builtin_amdgcn_mfma_f32_16x16x32_bf16(a0l, bh, acc[0][ct], 0, 0, 0);
            acc[0][ct] = __builtin_amdgcn_mfma_f32_16x16x32_bf16(a0h, bl, acc[0][ct], 0, 0, 0);
            acc[0][ct] = __builtin_amdgcn_mfma_f32_16x16x32_bf16(a0h, bh, acc[0][ct], 0, 0, 0);
            acc[1][ct] = __builtin_amdgcn_mfma_f32_16x16x32_bf16(a1l, bh, acc[1][ct], 0, 0, 0);
            acc[1][ct] = __builtin_amdgcn_mfma_f32_16x16x32_bf16(a1h, bl, acc[1][ct], 0, 0, 0);
            acc[1][ct] = __builtin_amdgcn_mfma_f32_16x16x32_bf16(a1h, bh, acc[1][ct], 0, 0, 0);
        }
    }

    // C/D layout (HW-verified): col = lane&15, row = (lane>>4)*4 + reg
    #pragma unroll
    for (int rt = 0; rt < 2; ++rt) {
        float no_[4];
        #pragma unroll
        for (int r = 0; r < 4; ++r) {
            int row = n0 + rt * 16 + g * 4 + r;
            no_[r] = (row < N_NODES) ? norm_out[row] : 0.f;
        }
        #pragma unroll
        for (int ct = 0; ct < 8; ++ct) {
            #pragma unroll
            for (int r = 0; r < 4; ++r) {
                int row = n0 + rt * 16 + g * 4 + r;
                if (row < N_NODES)
                    t1[(size_t)row * 128 + ct * 16 + lrow] = bf16_rne(acc[rt][ct][r] * no_[r]);
            }
        }
    }
}

// ---------------- GEMM-B via MFMA (bf16x3): t2 = fp16(h1p_fp16 @ W2) ----------------
// fp16 input: the hi/lo bf16 decomposition of an fp16 value is exact (11-bit
// mantissa fits in 8+8), so bf16x3 reproduces the fp16 product exactly.
__global__ __launch_bounds__(256) void gemmB_kernel(const unsigned short* __restrict__ h1p16,
                                                    const unsigned short* __restrict__ wf2_hi,
                                                    const unsigned short* __restrict__ wf2_lo,
                                                    unsigned short* __restrict__ t2h) {
    const int t  = threadIdx.x;
    const int wv = t >> 6;
    const int l  = t & 63;
    const int lrow = l & 15;
    const int g    = l >> 4;
    const int n0 = blockIdx.x * 128 + wv * 32;

    int r0 = n0 + lrow;      if (r0 > N_NODES - 1) r0 = N_NODES - 1;
    int r1 = n0 + 16 + lrow; if (r1 > N_NODES - 1) r1 = N_NODES - 1;
    const unsigned short* h0 = h1p16 + (size_t)r0 * 128 + g * 8;
    const unsigned short* h1 = h1p16 + (size_t)r1 * 128 + g * 8;

    f32x4 acc[2][4];
    #pragma unroll
    for (int rt = 0; rt < 2; ++rt)
        #pragma unroll
        for (int ct = 0; ct < 4; ++ct)
            acc[rt][ct] = (f32x4){0.f, 0.f, 0.f, 0.f};

    const bf16x8* bh_base = (const bf16x8*)wf2_hi;
    const bf16x8* bl_base = (const bf16x8*)wf2_lo;

    for (int ks = 0; ks < 4; ++ks) {
        unsigned short a0u[8], a1u[8];
        *(uint4*)a0u = *(const uint4*)(h0 + ks * 32);
        *(uint4*)a1u = *(const uint4*)(h1 + ks * 32);

        bf16x8 a0h, a0l, a1h, a1l;
        #pragma unroll
        for (int j = 0; j < 8; ++j) {
            float x0 = f16_val(a0u[j]);
            unsigned short hh = bf16_rne(x0);
            a0h[j] = (short)hh;
            a0l[j] = (short)bf16_rne(x0 - __uint_as_float((unsigned)hh << 16));
            float x1 = f16_val(a1u[j]);
            unsigned short h2 = bf16_rne(x1);
            a1h[j] = (short)h2;
            a1l[j] = (short)bf16_rne(x1 - __uint_as_float((unsigned)h2 << 16));
        }

        #pragma unroll
        for (int ct = 0; ct < 4; ++ct) {
            const int fi = (ks * 4 + ct) * 64 + l;
            bf16x8 bh = bh_base[fi];
            bf16x8 bl = bl_base[fi];
            acc[0][ct] = __builtin_amdgcn_mfma_f32_16x16x32_bf16(a0l, bh, acc[0][ct], 0, 0, 0);
            acc[0][ct] = __builtin_amdgcn_mfma_f32_16x16x32_bf16(a0h, bl, acc[0][ct], 0, 0, 0);
            acc[0][ct] = __builtin_amdgcn_mfma_f32_16x16x32_bf16(a0h, bh, acc[0][ct], 0, 0, 0);
            acc[1][ct] = __builtin_amdgcn_mfma_f32_16x16x32_bf16(a1l, bh, acc[1][ct], 0, 0, 0);
            acc[1][ct] = __builtin_amdgcn_mfma_f32_16x16x32_bf16(a1h, bl, acc[1][ct], 0, 0, 0);
            acc[1][ct] = __builtin_amdgcn_mfma_f32_16x16x32_bf16(a1h, bh, acc[1][ct], 0, 0, 0);
        }
    }

    #pragma unroll
    for (int rt = 0; rt < 2; ++rt) {
        #pragma unroll
        for (int ct = 0; ct < 4; ++ct) {
            #pragma unroll
            for (int r = 0; r < 4; ++r) {
                int row = n0 + rt * 16 + g * 4 + r;
                if (row < N_NODES)
                    t2h[(size_t)row * 64 + ct * 16 + lrow] = f16_bits(acc[rt][ct][r]);
            }
        }
    }
}

// ---------------- pull aggregation, 128 bf16 feats: one wave per node ----------------
// Pure gather+add (norm folded into t1); 8 gathers in flight; fp16 output row.
__global__ __launch_bounds__(256) void pull128_kernel(const unsigned short* __restrict__ xb,
                                                      const int* __restrict__ row_ptr,
                                                      const int* __restrict__ bsum,
                                                      const int* __restrict__ eidx,
                                                      const float* __restrict__ b1,
                                                      const float* __restrict__ norm_in,
                                                      const float* __restrict__ norm_out,
                                                      unsigned* __restrict__ out16) {
    int node = blockIdx.x * 4 + (threadIdx.x >> 6);
    node = __builtin_amdgcn_readfirstlane(node);
    const int lane = threadIdx.x & 63;
    const int beg = __builtin_amdgcn_readfirstlane(row_ptr[node] + bsum[node >> 8]);
    const int end = __builtin_amdgcn_readfirstlane(row_ptr[node + 1] + bsum[(node + 1) >> 8]);

    float2 acc0 = make_float2(0.f, 0.f);
    float2 acc1 = make_float2(0.f, 0.f);
    float2 acc2 = make_float2(0.f, 0.f);
    float2 acc3 = make_float2(0.f, 0.f);

    for (int base = beg; base < end; base += 64) {
        const int cnt = min(64, end - base);
        int my_e = (lane < cnt) ? eidx[base + lane] : 0;
        int k = 0;
        for (; k + 7 < cnt; k += 8) {
            int s0 = __builtin_amdgcn_readlane(my_e, k);
            int s1 = __builtin_amdgcn_readlane(my_e, k + 1);
            int s2 = __builtin_amdgcn_readlane(my_e, k + 2);
            int s3 = __builtin_amdgcn_readlane(my_e, k + 3);
            int s4 = __builtin_amdgcn_readlane(my_e, k + 4);
            int s5 = __builtin_amdgcn_readlane(my_e, k + 5);
            int s6 = __builtin_amdgcn_readlane(my_e, k + 6);
            int s7 = __builtin_amdgcn_readlane(my_e, k + 7);
            unsigned u0 = ((const unsigned*)(xb + (size_t)s0 * 128))[lane];
            unsigned u1 = ((const unsigned*)(xb + (size_t)s1 * 128))[lane];
            unsigned u2 = ((const unsigned*)(xb + (size_t)s2 * 128))[lane];
            unsigned u3 = ((const unsigned*)(xb + (size_t)s3 * 128))[lane];
            unsigned u4 = ((const unsigned*)(xb + (size_t)s4 * 128))[lane];
            unsigned u5 = ((const unsigned*)(xb + (size_t)s5 * 128))[lane];
            unsigned u6 = ((const unsigned*)(xb + (size_t)s6 * 128))[lane];
            unsigned u7 = ((const unsigned*)(xb + (size_t)s7 * 128))[lane];
            acc0.x += __uint_as_float(u0 << 16);
            acc0.y += __uint_as_float(u0 & 0xffff0000u);
            acc1.x += __uint_as_float(u1 << 16);
            acc1.y += __uint_as_float(u1 & 0xffff0000u);
            acc2.x += __uint_as_float(u2 << 16);
            acc2.y += __uint_as_float(u2 & 0xffff0000u);
            acc3.x += __uint_as_float(u3 << 16);
            acc3.y += __uint_as_float(u3 & 0xffff0000u);
            acc0.x += __uint_as_float(u4 << 16);
            acc0.y += __uint_as_float(u4 & 0xffff0000u);
            acc1.x += __uint_as_float(u5 << 16);
            acc1.y += __uint_as_float(u5 & 0xffff0000u);
            acc2.x += __uint_as_float(u6 << 16);
            acc2.y += __uint_as_float(u6 & 0xffff0000u);
            acc3.x += __uint_as_float(u7 << 16);
            acc3.y += __uint_as_float(u7 & 0xffff0000u);
        }
        for (; k + 3 < cnt; k += 4) {
            int s0 = __builtin_amdgcn_readlane(my_e, k);
            int s1 = __builtin_amdgcn_readlane(my_e, k + 1);
            int s2 = __builtin_amdgcn_readlane(my_e, k + 2);
            int s3 = __builtin_amdgcn_readlane(my_e, k + 3);
            unsigned u0 = ((const unsigned*)(xb + (size_t)s0 * 128))[lane];
            unsigned u1 = ((const unsigned*)(xb + (size_t)s1 * 128))[lane];
            unsigned u2 = ((const unsigned*)(xb + (size_t)s2 * 128))[lane];
            unsigned u3 = ((const unsigned*)(xb + (size_t)s3 * 128))[lane];
            acc0.x += __uint_as_float(u0 << 16);
            acc0.y += __uint_as_float(u0 & 0xffff0000u);
            acc1.x += __uint_as_float(u1 << 16);
            acc1.y += __uint_as_float(u1 & 0xffff0000u);
            acc2.x += __uint_as_float(u2 << 16);
            acc2.y += __uint_as_float(u2 & 0xffff0000u);
            acc3.x += __uint_as_float(u3 << 16);
            acc3.y += __uint_as_float(u3 & 0xffff0000u);
        }
        for (; k < cnt; ++k) {
            int s0 = __builtin_amdgcn_readlane(my_e, k);
            unsigned u0 = ((const unsigned*)(xb + (size_t)s0 * 128))[lane];
            acc0.x += __uint_as_float(u0 << 16);
            acc0.y += __uint_as_float(u0 & 0xffff0000u);
        }
    }

    float ni = norm_in[node];
    float no = norm_out[node];
    float2 bb = ((const float2*)b1)[lane];
    float sx = (acc0.x + acc1.x) + (acc2.x + acc3.x);
    float sy = (acc0.y + acc1.y) + (acc2.y + acc3.y);
    float rx = fmaxf(fmaf(sx, ni, bb.x), 0.f) * no;
    float ry = fmaxf(fmaf(sy, ni, bb.y), 0.f) * no;
    unsigned pw = (unsigned)f16_bits(rx) | ((unsigned)f16_bits(ry) << 16);
    out16[(size_t)node * 64 + lane] = pw;
}

// ---------------- pull aggregation, 64 fp16 feats, 2 edges per wave-round ----------------
__global__ __launch_bounds__(256) void pull64_kernel(const unsigned* __restrict__ x,
                                                     const int* __restrict__ row_ptr,
                                                     const int* __restrict__ bsum,
                                                     const int* __restrict__ eidx,
                                                     const float* __restrict__ b2,
                                                     const float* __restrict__ norm_in,
                                                     float* __restrict__ out) {
    int node = blockIdx.x * 4 + (threadIdx.x >> 6);
    node = __builtin_amdgcn_readfirstlane(node);
    const int lane = threadIdx.x & 63;
    const int half = lane >> 5;
    const int fl = lane & 31;
    const int beg = __builtin_amdgcn_readfirstlane(row_ptr[node] + bsum[node >> 8]);
    const int end = __builtin_amdgcn_readfirstlane(row_ptr[node + 1] + bsum[(node + 1) >> 8]);

    float2 a0 = make_float2(0.f, 0.f);
    float2 a1 = make_float2(0.f, 0.f);
    float2 a2 = make_float2(0.f, 0.f);
    float2 a3 = make_float2(0.f, 0.f);

    for (int base = beg; base < end; base += 64) {
        const int cnt = min(64, end - base);
        int my_e = (lane < cnt) ? eidx[base + lane] : 0;
        int k = 0;
        for (; k + 7 < cnt; k += 8) {
            int sa0 = __builtin_amdgcn_readlane(my_e, k);
            int sb0 = __builtin_amdgcn_readlane(my_e, k + 1);
            int sa1 = __builtin_amdgcn_readlane(my_e, k + 2);
            int sb1 = __builtin_amdgcn_readlane(my_e, k + 3);
            int sa2 = __builtin_amdgcn_readlane(my_e, k + 4);
            int sb2 = __builtin_amdgcn_readlane(my_e, k + 5);
            int sa3 = __builtin_amdgcn_readlane(my_e, k + 6);
            int sb3 = __builtin_amdgcn_readlane(my_e, k + 7);
            int e0 = half ? sb0 : sa0;
            int e1 = half ? sb1 : sa1;
            int e2 = half ? sb2 : sa2;
            int e3 = half ? sb3 : sa3;
            unsigned u0 = x[(size_t)e0 * 32 + fl];
            unsigned u1 = x[(size_t)e1 * 32 + fl];
            unsigned u2 = x[(size_t)e2 * 32 + fl];
            unsigned u3 = x[(size_t)e3 * 32 + fl];
            float2 v0 = unpack_f16x2(u0);
            float2 v1 = unpack_f16x2(u1);
            float2 v2 = unpack_f16x2(u2);
            float2 v3 = unpack_f16x2(u3);
            a0.x += v0.x; a0.y += v0.y;
            a1.x += v1.x; a1.y += v1.y;
            a2.x += v2.x; a2.y += v2.y;
            a3.x += v3.x; a3.y += v3.y;
        }
        for (; k + 1 < cnt; k += 2) {
            int sa = __builtin_amdgcn_readlane(my_e, k);
            int sb = __builtin_amdgcn_readlane(my_e, k + 1);
            int e0 = half ? sb : sa;
            unsigned u = x[(size_t)e0 * 32 + fl];
            float2 v = unpack_f16x2(u);
            a0.x += v.x; a0.y += v.y;
        }
        if (k < cnt) {
            int sa = __builtin_amdgcn_readlane(my_e, k);
            if (half == 0) {
                unsigned u = x[(size_t)sa * 32 + fl];
                float2 v = unpack_f16x2(u);
                a0.x += v.x; a0.y += v.y;
            }
        }
    }

    float ax = (a0.x + a1.x) + (a2.x + a3.x);
    float ay = (a0.y + a1.y) + (a2.y + a3.y);
    ax += __shfl_xor(ax, 32, 64);
    ay += __shfl_xor(ay, 32, 64);
    if (half == 0) {
        float ni = norm_in[node];
        float2 bb = ((const float2*)b2)[fl];
        float2 r;
        r.x = fmaxf(fmaf(ax, ni, bb.x), 0.f);
        r.y = fmaxf(fmaf(ay, ni, bb.y), 0.f);
        ((float2*)(out + (size_t)node * 64))[fl] = r;
    }
}

extern "C" void kernel_launch(void* const* d_in, const int* in_sizes, int n_in,
                              void* d_out, int out_size, void* d_ws, size_t ws_size,
                              hipStream_t stream) {
    const float* h  = (const float*)d_in[0];
    const float* W1 = (const float*)d_in[1];
    const float* b1 = (const float*)d_in[2];
    const float* W2 = (const float*)d_in[3];
    const float* b2 = (const float*)d_in[4];
    const int* src  = (const int*)d_in[5];
    const int* dst  = (const int*)d_in[6];
    float* out = (float*)d_out;

    char* ws = (char*)d_ws;
    size_t off = 0;
    auto alloc = [&](size_t bytes) {
        void* p = ws + off;
        off = (off + bytes + 255) & ~(size_t)255;
        return p;
    };
    float* norm_out   = (float*)alloc(N_NODES * sizeof(float));
    float* norm_in    = (float*)alloc(N_NODES * sizeof(float));
    int* row_ptr      = (int*)alloc((N_NODES + 1) * sizeof(int));
    int* bsum         = (int*)alloc(NBS * sizeof(int));
    unsigned short* wf_hi  = (unsigned short*)alloc(2048 * 16);
    unsigned short* wf_lo  = (unsigned short*)alloc(2048 * 16);
    unsigned short* wf2_hi = (unsigned short*)alloc(1024 * 16);
    unsigned short* wf2_lo = (unsigned short*)alloc(1024 * 16);
    int* eidx         = (int*)alloc((size_t)N_EDGES * sizeof(int));                       // 3.2 MB
    unsigned short* t1 = (unsigned short*)alloc((size_t)N_NODES * 128 * sizeof(short));   // 12.8 MB
    // region below holds hist scratch first, then fp16 h1p (13.6 MB needed for scratch)
    unsigned char* scratch = (unsigned char*)alloc(26 * 1024 * 1024);                     // 26 MB

    unsigned char* cntD = scratch;                                // 6.4 MB
    unsigned char* cntS = cntD + (size_t)CHUNKS * 50000;          // 6.4 MB
    unsigned char* rp   = cntS + (size_t)CHUNKS * 50000;          // 0.8 MB
    unsigned short* h1p16 = (unsigned short*)scratch;             // 12.8 MB fp16 h1p (scratch dead after place)
    unsigned short* t2h = t1;                                     // t1 dead after pull128

    // launch 1: histogram half-chunks || W-pack
    hist_wpack_kernel<<<2 * CHUNKS + 3, 1024, 0, stream>>>(src, dst, cntD, cntS, rp,
                                                           W1, W2, wf_hi, wf_lo,
                                                           wf2_hi, wf2_lo);

    // launch 2: per-node chunk prefix + norms + block scan
    deg_scan_kernel<<<NBS, 256, 0, stream>>>(cntD, cntS, row_ptr, bsum, norm_out, norm_in);

    // launch 3: scan of block sums (also writes row_ptr[N_NODES])
    scan2_kernel<<<1, 64, 0, stream>>>(bsum, row_ptr);

    // launch 4: gemmA (MFMA bf16x3, norm folded) || CSR placement
    gemmA_place_kernel<<<GA_BLOCKS + PLACE_BLOCKS, 256, 0, stream>>>(
        h, wf_hi, wf_lo, norm_out, t1, src, dst, row_ptr, bsum, cntD, rp, eidx);

    // launch 5: layer 1 pull (bf16 gather+add, fp16 output) — overwrites hist scratch
    pull128_kernel<<<N_NODES / 4, 256, 0, stream>>>(t1, row_ptr, bsum, eidx, b1,
                                                    norm_in, norm_out, (unsigned*)h1p16);

    // launch 6: gemmB (MFMA bf16x3 on fp16 input)
    gemmB_kernel<<<GA_BLOCKS, 256, 0, stream>>>(h1p16, wf2_hi, wf2_lo, t2h);

    // launch 7: layer 2 pull
    pull64_kernel<<<N_NODES / 4, 256, 0, stream>>>((const unsigned*)t2h, row_ptr, bsum, eidx,
                                                   b2, norm_in, out);
}